// Round 8
// baseline (3418.078 us; speedup 1.0000x reference)
//
#include <hip/hip_runtime.h>
#include <math.h>

#define Bsz 64
#define Tn 64
#define Ln 100
#define Dn 128
#define An 18
#define Hn 512
#define NGRP 16

__device__ __forceinline__ float sigf(float x){ return 1.0f/(1.0f+expf(-x)); }

__device__ __forceinline__ void scst(float* p, float v){
  __hip_atomic_store(p, v, __ATOMIC_RELAXED, __HIP_MEMORY_SCOPE_AGENT);
}
__device__ __forceinline__ void scsti(int* p, int v){
  __hip_atomic_store(p, v, __ATOMIC_RELAXED, __HIP_MEMORY_SCOPE_AGENT);
}
__device__ __forceinline__ int lcldi(const int* p){
  return __hip_atomic_load((int*)p, __ATOMIC_RELAXED, __HIP_MEMORY_SCOPE_AGENT);
}

// split barrier: arrive (relaxed bypass add) / wait (relaxed spin). Caller
// guarantees its cross-block stores are drained before arrive (vmcnt(0) by the
// storing wave, or __syncthreads for multi-wave stores). Readers use cached
// loads of write-once addresses -> no cache maintenance needed.
__device__ __forceinline__ void gbar_arrive(int* grp_arr, int* grp_gen, int* root, int nb, int ph){
  const int gs = nb >> 4;
  const int g  = (int)blockIdx.x & 15;
  int a = __hip_atomic_fetch_add(grp_arr + g*64, 1, __ATOMIC_RELAXED, __HIP_MEMORY_SCOPE_AGENT) + 1;
  if (a == ph*gs){
    int r = __hip_atomic_fetch_add(root, 1, __ATOMIC_RELAXED, __HIP_MEMORY_SCOPE_AGENT) + 1;
    if (r == ph*NGRP){
      #pragma unroll
      for (int i = 0; i < NGRP; i++) scsti(grp_gen + i*64, ph);
    }
  }
}
__device__ __forceinline__ void gbar_wait(int* grp_gen, int ph){
  const int g = (int)blockIdx.x & 15;
  while (lcldi(grp_gen + g*64) < ph) __builtin_amdgcn_s_sleep(1);
}
// full barrier for multi-wave-store phases (syncthreads drains all waves' vmcnt)
__device__ __forceinline__ void gbarH(int* gA, int* gG, int* gR, int nb, int ph){
  __syncthreads();
  if (threadIdx.x == 0){
    asm volatile("s_waitcnt vmcnt(0) lgkmcnt(0)" ::: "memory");
    gbar_arrive(gA, gG, gR, nb, ph);
    gbar_wait(gG, ph);
  }
  __syncthreads();
}

// ---------- demo transpose: demoT[l][b][d] = demo[0][b][l][d] ----------
__global__ __launch_bounds__(256) void demo_transpose_kernel(
    const float* __restrict__ demo, float* __restrict__ demoT)
{
  int idx = blockIdx.x*256 + threadIdx.x;
  if (idx < Ln*Bsz*Dn) {
    int d = idx & 127;
    int b = (idx >> 7) & 63;
    int l = idx >> 13;
    demoT[idx] = demo[((size_t)(b*Ln + l))*Dn + d];
  }
}

// ---------- generic tiled GEMM: C[M][N] = A[M][K] * B[N][K]^T + bias[n] ----------
__global__ __launch_bounds__(256) void gemm_nt_kernel(
    const float* __restrict__ A, int lda,
    const float* __restrict__ B, int ldb,
    const float* __restrict__ bias,
    float* __restrict__ C, int ldc, int K)
{
  __shared__ float As[64][17];
  __shared__ float Bs[64][17];
  const int m0 = blockIdx.x * 64;
  const int n0 = blockIdx.y * 64;
  const int tx = threadIdx.x & 15;
  const int ty = threadIdx.x >> 4;
  float acc[4][4] = {};
  for (int k0 = 0; k0 < K; k0 += 16) {
    #pragma unroll
    for (int i = 0; i < 4; i++) {
      int e = threadIdx.x + i*256;
      int r = e >> 4, c = e & 15;
      As[r][c] = A[(size_t)(m0 + r)*lda + k0 + c];
      Bs[r][c] = B[(size_t)(n0 + r)*ldb + k0 + c];
    }
    __syncthreads();
    #pragma unroll
    for (int kk = 0; kk < 16; kk++) {
      float a0 = As[ty*4+0][kk], a1 = As[ty*4+1][kk], a2 = As[ty*4+2][kk], a3 = As[ty*4+3][kk];
      float b0 = Bs[tx*4+0][kk], b1 = Bs[tx*4+1][kk], b2 = Bs[tx*4+2][kk], b3 = Bs[tx*4+3][kk];
      acc[0][0] += a0*b0; acc[0][1] += a0*b1; acc[0][2] += a0*b2; acc[0][3] += a0*b3;
      acc[1][0] += a1*b0; acc[1][1] += a1*b1; acc[1][2] += a1*b2; acc[1][3] += a1*b3;
      acc[2][0] += a2*b0; acc[2][1] += a2*b1; acc[2][2] += a2*b2; acc[2][3] += a2*b3;
      acc[3][0] += a3*b0; acc[3][1] += a3*b1; acc[3][2] += a3*b2; acc[3][3] += a3*b3;
    }
    __syncthreads();
  }
  #pragma unroll
  for (int i = 0; i < 4; i++) {
    #pragma unroll
    for (int j = 0; j < 4; j++) {
      int nn = n0 + tx*4 + j;
      float v = acc[i][j] + (bias ? bias[nn] : 0.0f);
      C[(size_t)(m0 + ty*4 + i)*ldc + nn] = v;
    }
  }
}

// ---------- head fold: M2 = out_W @ mid_W  [An][Hn]; bias2 = out_b + mid_b@out_W^T ----------
__global__ __launch_bounds__(512) void head_fold_kernel(
    const float* __restrict__ mid_W, const float* __restrict__ mid_b,
    const float* __restrict__ out_W, const float* __restrict__ out_b,
    float* __restrict__ M2, float* __restrict__ bias2)
{
  const int a = blockIdx.x;
  const int k = threadIdx.x;
  const float* ow = out_W + (size_t)a*Hn;
  float s = 0.f;
  #pragma unroll 4
  for (int n = 0; n < Hn; n++) s += ow[n]*mid_W[(size_t)n*Hn + k];
  M2[(size_t)a*Hn + k] = s;
  if (k == 0){
    float b2 = out_b[a];
    for (int n = 0; n < Hn; n++) b2 += ow[n]*mid_b[n];
    bias2[a] = b2;
  }
}

// ---------- q head: q[t][b][a] = hhist[t][b] . M2[a] + bias2[a] ----------
__global__ __launch_bounds__(256) void qhead_kernel(
    const float* __restrict__ hhist, const float* __restrict__ M2,
    const float* __restrict__ bias2, float* __restrict__ q)
{
  const int t = blockIdx.x;
  for (int p = threadIdx.x; p < Bsz*An; p += 256){
    int b = p / An, a = p % An;
    const float4* hv = (const float4*)(hhist + ((size_t)t*Bsz + b)*Hn);
    const float4* mv = (const float4*)(M2 + (size_t)a*Hn);
    float s = bias2[a];
    #pragma unroll 8
    for (int k = 0; k < Hn/4; k++){
      float4 H = hv[k], M = mv[k];
      s += H.x*M.x + H.y*M.y + H.z*M.z + H.w*M.w;
    }
    q[((size_t)(t*Bsz + b))*An + a] = s;
  }
}

// ---------- persistent fused encoder: 256 blocks x 512 threads, LDS weights ----------
__global__ __launch_bounds__(512, 1) void enc_scan_kernel(
    const float* __restrict__ demoT,   // [Ln][Bsz][Dn]
    const float* __restrict__ Wih, const float* __restrict__ Whh,
    const float* __restrict__ bih, const float* __restrict__ bhh,
    const float* __restrict__ attn_W, const float* __restrict__ attn_b,
    const float* __restrict__ comb_W,
    float* __restrict__ hencR,         // [Ln][Bsz][Hn]  per-step write-once
    float* __restrict__ attnp,         // [Bsz][Ln][Hn]
    float* __restrict__ CE,            // [Bsz][Ln][Hn]
    int* __restrict__ gA, int* __restrict__ gG, int* __restrict__ gR)
{
  const int bid  = blockIdx.x;
  const int tid  = threadIdx.x;
  const int lane = tid & 63;
  const int ks   = tid >> 6;          // 0..7
  const int n0   = bid*2;

  __shared__ float lds_whh[8][Hn];
  __shared__ float lds_wih[8][Dn];
  __shared__ float lds_atw[2][Hn];
  __shared__ float lds_cbw[2][Hn];
  __shared__ float red[8][12][Bsz];

  #pragma unroll
  for (int c = 0; c < 2; c++)
    #pragma unroll
    for (int g = 0; g < 4; g++){
      int r = c*4 + g;
      lds_whh[r][tid] = Whh[(size_t)(g*Hn + n0 + c)*Hn + tid];
      if (tid < Dn) lds_wih[r][tid] = Wih[(size_t)(g*Hn + n0 + c)*Dn + tid];
    }
  #pragma unroll
  for (int c = 0; c < 2; c++){
    lds_atw[c][tid] = attn_W[(size_t)(n0 + c)*Hn + tid];
    lds_cbw[c][tid] = comb_W[(size_t)(n0 + c)*(Hn + Dn) + tid];
  }
  float bsum[2][4];
  #pragma unroll
  for (int c = 0; c < 2; c++)
    #pragma unroll
    for (int g = 0; g < 4; g++){
      int r = g*Hn + n0 + c;
      bsum[c][g] = bih[r] + bhh[r];
    }
  const float ab[2] = { attn_b[n0], attn_b[n0+1] };
  float cr[2] = {0.f, 0.f};
  __syncthreads();

  for (int l = 0; l <= Ln; l++){
    // ---- recurrence-critical: gates -> h(l) -> early arrive ----
    if (l < Ln){
      float a[2][4] = {{0,0,0,0},{0,0,0,0}};
      if (l >= 1){
        const float4* hv = (const float4*)(hencR + ((size_t)(l-1)*Bsz + lane)*Hn) + ks*16;
        #pragma unroll 4
        for (int q = 0; q < 16; q++){
          float4 H = hv[q];
          #pragma unroll
          for (int c = 0; c < 2; c++)
            #pragma unroll
            for (int g = 0; g < 4; g++){
              float4 W = *(const float4*)&lds_whh[c*4+g][ks*64 + 4*q];
              a[c][g] += H.x*W.x + H.y*W.y + H.z*W.z + H.w*W.w;
            }
        }
      }
      {
        const float4* dv = (const float4*)(demoT + ((size_t)l*Bsz + lane)*Dn) + ks*4;
        #pragma unroll
        for (int q = 0; q < 4; q++){
          float4 V = dv[q];
          #pragma unroll
          for (int c = 0; c < 2; c++)
            #pragma unroll
            for (int g = 0; g < 4; g++){
              float4 W = *(const float4*)&lds_wih[c*4+g][ks*16 + 4*q];
              a[c][g] += V.x*W.x + V.y*W.y + V.z*W.z + V.w*W.w;
            }
        }
      }
      #pragma unroll
      for (int c = 0; c < 2; c++)
        #pragma unroll
        for (int g = 0; g < 4; g++) red[ks][c*4+g][lane] = a[c][g];
      __syncthreads();
      if (tid < Bsz){
        int b = tid;
        #pragma unroll
        for (int c = 0; c < 2; c++){
          float g0 = bsum[c][0], g1 = bsum[c][1], g2 = bsum[c][2], g3 = bsum[c][3];
          #pragma unroll
          for (int k = 0; k < 8; k++){
            g0 += red[k][c*4+0][b]; g1 += red[k][c*4+1][b];
            g2 += red[k][c*4+2][b]; g3 += red[k][c*4+3][b];
          }
          float ii = sigf(g0), ff = sigf(g1), gg = tanhf(g2), oo = sigf(g3);
          float cn = ff*cr[c] + ii*gg;
          float hn = oo*tanhf(cn);
          cr[c] = cn;
          scst(hencR + ((size_t)l*Bsz + b)*Hn + n0 + c, hn);
        }
      }
      // h written only by wave 0; tid0 is in wave 0 -> wave-local drain suffices
      if (tid == 0){
        asm volatile("s_waitcnt vmcnt(0)" ::: "memory");
        gbar_arrive(gA, gG, gR, (int)gridDim.x, l+1);
      }
    }
    // ---- off-critical-path: attnp/CE for step l-1 (H reload hits L1) ----
    if (l >= 1){
      float aa[2] = {0,0}, ac[2] = {0,0};
      const float4* hv = (const float4*)(hencR + ((size_t)(l-1)*Bsz + lane)*Hn) + ks*16;
      #pragma unroll 4
      for (int q = 0; q < 16; q++){
        float4 H = hv[q];
        #pragma unroll
        for (int c = 0; c < 2; c++){
          float4 Aw = *(const float4*)&lds_atw[c][ks*64 + 4*q];
          aa[c] += H.x*Aw.x + H.y*Aw.y + H.z*Aw.z + H.w*Aw.w;
          float4 Cw = *(const float4*)&lds_cbw[c][ks*64 + 4*q];
          ac[c] += H.x*Cw.x + H.y*Cw.y + H.z*Cw.z + H.w*Cw.w;
        }
      }
      #pragma unroll
      for (int c = 0; c < 2; c++){
        red[ks][8+c][lane]  = aa[c];
        red[ks][10+c][lane] = ac[c];
      }
      __syncthreads();
      if (tid < Bsz){
        int b = tid;
        #pragma unroll
        for (int c = 0; c < 2; c++){
          float av = ab[c], cv = 0.f;
          #pragma unroll
          for (int k = 0; k < 8; k++){ av += red[k][8+c][b]; cv += red[k][10+c][b]; }
          scst(attnp + ((size_t)(b*Ln + (l-1)))*Hn + n0 + c, av);
          scst(CE    + ((size_t)(b*Ln + (l-1)))*Hn + n0 + c, cv);
        }
      }
    }
    if (l < Ln){
      if (tid == 0) gbar_wait(gG, l+1);
      __syncthreads();
    }
  }
}

// ---------- persistent decoder: 256 blocks x 512 threads, LDS weights ----------
__global__ __launch_bounds__(512, 1) void dec_scan_kernel(
    const float* __restrict__ h0, const float* __restrict__ c0,
    const float* __restrict__ attnp,   // [Bsz][Ln][Hn]
    const float* __restrict__ CE,      // [Bsz][Ln][Hn]
    const float* __restrict__ preobs,  // [Tn*Bsz][Hn]
    const int*   __restrict__ dlen,
    const float* __restrict__ lstm_Wih, const float* __restrict__ lstm_Whh,
    const float* __restrict__ lstm_bih, const float* __restrict__ lstm_bhh,
    const float* __restrict__ comb_b,
    float* __restrict__ xrow,          // [Tn][Bsz][Hn]  per-step write-once
    float* __restrict__ hhist,         // [Tn][Bsz][Hn]  per-step write-once
    float* __restrict__ outp,
    int* __restrict__ gA, int* __restrict__ gG, int* __restrict__ gR)
{
  const int bid  = blockIdx.x;
  const int tid  = threadIdx.x;
  const int lane = tid & 63;
  const int ks   = tid >> 6;          // 0..7
  const int n0   = bid*2;

  __shared__ float lds_wi[8][Hn];
  __shared__ float lds_wh[8][Hn];
  __shared__ float hs[Hn];
  __shared__ float wls[128];
  __shared__ float mx_s, sum_s;
  __shared__ float red[8][8][Bsz];

  #pragma unroll
  for (int c = 0; c < 2; c++)
    #pragma unroll
    for (int g = 0; g < 4; g++){
      int r = c*4 + g;
      lds_wi[r][tid] = lstm_Wih[(size_t)(g*Hn + n0 + c)*Hn + tid];
      lds_wh[r][tid] = lstm_Whh[(size_t)(g*Hn + n0 + c)*Hn + tid];
    }
  float bs[2][4];
  #pragma unroll
  for (int c = 0; c < 2; c++)
    #pragma unroll
    for (int g = 0; g < 4; g++){
      int r = g*Hn + n0 + c;
      bs[c][g] = lstm_bih[r] + lstm_bhh[r];
    }
  float cr[2] = {0.f, 0.f};
  int ph = 0;
  __syncthreads();

  for (int t = 0; t < Tn; t++){
    const float* hprev_all = (t == 0) ? h0 : (hhist + (size_t)(t-1)*Bsz*Hn);

    // ============ Phase 1: attention (blocks 0..63) + Whh@h partial (ALL) ============
    if (bid < Bsz){
      const int b = bid;
      hs[tid] = hprev_all[(size_t)b*Hn + tid];
      if (tid >= 100 && tid < 128) wls[tid] = -1e30f;
      __syncthreads();
      const int len = dlen[b];
      if (tid < 400){
        int l = tid >> 2, kh = tid & 3;
        const float4* ap = (const float4*)(attnp + ((size_t)(b*Ln + l))*Hn) + kh*32;
        const float4* hv = (const float4*)hs + kh*32;
        float s = 0.f;
        #pragma unroll 8
        for (int k = 0; k < 32; k++){
          float4 A = ap[k], H = hv[k];
          s += A.x*H.x + A.y*H.y + A.z*H.z + A.w*H.w;
        }
        s += __shfl_xor(s, 1);
        s += __shfl_xor(s, 2);
        if (kh == 0) wls[l] = (l < len) ? s*0.1f : -1e30f;
      }
      __syncthreads();
      if (tid < 64){
        float v = fmaxf(wls[tid], wls[tid+64]);
        for (int off = 1; off < 64; off <<= 1) v = fmaxf(v, __shfl_xor(v, off));
        if (tid == 0) mx_s = v;
      }
      __syncthreads();
      float mx = mx_s;
      if (tid < 64){
        float e0 = (wls[tid]    > -1e29f) ? expf(wls[tid]    - mx) : 0.f;
        float e1 = (wls[tid+64] > -1e29f) ? expf(wls[tid+64] - mx) : 0.f;
        wls[tid] = e0; wls[tid+64] = e1;   // exact 0.0 beyond len
        float v = e0 + e1;
        for (int off = 1; off < 64; off <<= 1) v += __shfl_xor(v, off);
        if (tid == 0) sum_s = v;
      }
      __syncthreads();
      float inv = 1.0f / sum_s;
      {
        int n = tid;
        const float* cb = CE + (size_t)b*Ln*Hn + n;
        float acc = 0.f;
        #pragma unroll 4
        for (int l2 = 0; l2 < Ln; ++l2) acc += cb[(size_t)l2*Hn]*wls[l2];  // static trip
        float v = acc*inv + preobs[((size_t)(t*Bsz + b))*Hn + n] + comb_b[n];
        scst(xrow + ((size_t)t*Bsz + b)*Hn + n, fmaxf(v, 0.f));
      }
    }
    // all blocks: Whh @ h(t-1) partial for own 2 columns; kept in VGPRs across barrier
    float hpa[2][4] = {{0,0,0,0},{0,0,0,0}};
    {
      const float4* hv = (const float4*)(hprev_all + (size_t)lane*Hn) + ks*16;
      #pragma unroll 4
      for (int q = 0; q < 16; q++){
        float4 H = hv[q];
        #pragma unroll
        for (int c = 0; c < 2; c++)
          #pragma unroll
          for (int g = 0; g < 4; g++){
            float4 W = *(const float4*)&lds_wh[c*4+g][ks*64 + 4*q];
            hpa[c][g] += H.x*W.x + H.y*W.y + H.z*W.z + H.w*W.w;
          }
      }
    }
    gbarH(gA, gG, gR, (int)gridDim.x, ++ph);   // x written by all waves -> full barrier

    // ============ Phase 2: += Wih@x; reduce; cell ============
    {
      const float4* xv = (const float4*)(xrow + ((size_t)t*Bsz + lane)*Hn) + ks*16;
      #pragma unroll 4
      for (int q = 0; q < 16; q++){
        float4 X = xv[q];
        #pragma unroll
        for (int c = 0; c < 2; c++)
          #pragma unroll
          for (int g = 0; g < 4; g++){
            float4 W = *(const float4*)&lds_wi[c*4+g][ks*64 + 4*q];
            hpa[c][g] += X.x*W.x + X.y*W.y + X.z*W.z + X.w*W.w;
          }
      }
      #pragma unroll
      for (int c = 0; c < 2; c++)
        #pragma unroll
        for (int g = 0; g < 4; g++) red[ks][c*4+g][lane] = hpa[c][g];
      __syncthreads();
      if (tid < Bsz){
        int b = tid;
        #pragma unroll
        for (int c = 0; c < 2; c++){
          int n = n0 + c;
          if (t == 0) cr[c] = c0[(size_t)b*Hn + n];
          float g0 = bs[c][0], g1 = bs[c][1], g2 = bs[c][2], g3 = bs[c][3];
          #pragma unroll
          for (int k = 0; k < 8; k++){
            g0 += red[k][c*4+0][b]; g1 += red[k][c*4+1][b];
            g2 += red[k][c*4+2][b]; g3 += red[k][c*4+3][b];
          }
          float ii = sigf(g0), ff = sigf(g1), gg = tanhf(g2), oo = sigf(g3);
          float cn = ff*cr[c] + ii*gg;
          float hn = oo*tanhf(cn);
          cr[c] = cn;
          scst(hhist + ((size_t)t*Bsz + b)*Hn + n, hn);
          if (t == Tn - 1){
            outp[Tn*Bsz*An + (size_t)b*Hn + n]           = hn;
            outp[Tn*Bsz*An + Bsz*Hn + (size_t)b*Hn + n]  = cn;
          }
        }
      }
      // h written only by wave 0 -> wave-local drain + early arrive
      if (t < Tn - 1){
        if (tid == 0){
          asm volatile("s_waitcnt vmcnt(0)" ::: "memory");
          gbar_arrive(gA, gG, gR, (int)gridDim.x, ph+1);
          gbar_wait(gG, ph+1);
        }
        ph++;
        __syncthreads();
      }
    }
  }
}

extern "C" void kernel_launch(void* const* d_in, const int* in_sizes, int n_in,
                              void* d_out, int out_size, void* d_ws, size_t ws_size,
                              hipStream_t stream) {
  (void)in_sizes; (void)n_in; (void)out_size; (void)ws_size;
  const float* state    = (const float*)d_in[0];
  const float* demo     = (const float*)d_in[1];
  const int*   dlen     = (const int*)  d_in[2];
  const float* h0       = (const float*)d_in[5];
  const float* c0       = (const float*)d_in[6];
  const float* enc_Wih  = (const float*)d_in[7];
  const float* enc_Whh  = (const float*)d_in[8];
  const float* enc_bih  = (const float*)d_in[9];
  const float* enc_bhh  = (const float*)d_in[10];
  const float* attn_W   = (const float*)d_in[11];
  const float* attn_b   = (const float*)d_in[12];
  const float* comb_W   = (const float*)d_in[13];
  const float* comb_b   = (const float*)d_in[14];
  const float* lstm_Wih = (const float*)d_in[15];
  const float* lstm_Whh = (const float*)d_in[16];
  const float* lstm_bih = (const float*)d_in[17];
  const float* lstm_bhh = (const float*)d_in[18];
  const float* mid_W    = (const float*)d_in[19];
  const float* mid_b    = (const float*)d_in[20];
  const float* out_W    = (const float*)d_in[21];
  const float* out_b    = (const float*)d_in[22];
  float* ws   = (float*)d_ws;
  float* qout = (float*)d_out;

  // workspace layout (f32 words)
  float* attnp  = ws + 0;         // 3,276,800  [B][L][H]
  float* CE     = ws + 3276800;   // 3,276,800  [B][L][H]
  float* preobs = ws + 6553600;   // 2,097,152  [T*B][H]
  float* region = ws + 8650752;   // 4,194,304 shared region:
  float* demoT  = region;                  // enc: 819,200   [L][B][D]
  float* hencR  = region + 819200;         // enc: 3,276,800 [L][B][H]
  float* xrow   = region;                  // dec: 2,097,152 [T][B][H]
  float* hhist  = region + 2097152;        // dec: 2,097,152 [T][B][H]
  int*   barB   = (int*)(ws + 12845056);   // 4224 ints
  int* encA = barB;          int* encG = barB + 1024; int* encR = barB + 2048;
  int* decA = barB + 2112;   int* decG = barB + 3136; int* decR = barB + 4160;
  float* M2    = ws + 12850176;   // 9,216  [An][Hn]
  float* bias2 = ws + 12859392;   // 18

  hipMemsetAsync((void*)barB, 0, 4224*4, stream);

  demo_transpose_kernel<<<3200, 256, 0, stream>>>(demo, demoT);

  // fold mid+out heads: M2 = out_W@mid_W, bias2 = out_b + mid_b@out_W^T
  head_fold_kernel<<<An, 512, 0, stream>>>(mid_W, mid_b, out_W, out_b, M2, bias2);

  // preobs[(t,b)][n] = state[t,b,:] . comb_W[n, 512:640]
  gemm_nt_kernel<<<dim3(Tn*Bsz/64, Hn/64), 256, 0, stream>>>(
      state, Dn, comb_W + Hn, Hn + Dn, nullptr, preobs, Hn, Dn);

  enc_scan_kernel<<<256, 512, 0, stream>>>(
      demoT, enc_Wih, enc_Whh, enc_bih, enc_bhh, attn_W, attn_b, comb_W,
      hencR, attnp, CE, encA, encG, encR);

  dec_scan_kernel<<<256, 512, 0, stream>>>(
      h0, c0, attnp, CE, preobs, dlen, lstm_Wih, lstm_Whh, lstm_bih, lstm_bhh,
      comb_b, xrow, hhist, qout, decA, decG, decR);

  // q = hhist @ M2^T + bias2
  qhead_kernel<<<Tn, 256, 0, stream>>>(hhist, M2, bias2, qout);
}

// Round 9
// 3177.662 us; speedup vs baseline: 1.0757x; 1.0757x over previous
//
#include <hip/hip_runtime.h>
#include <math.h>

#define Bsz 64
#define Tn 64
#define Ln 100
#define Dn 128
#define An 18
#define Hn 512
#define NGRP 16

__device__ __forceinline__ float sigf(float x){ return 1.0f/(1.0f+expf(-x)); }

__device__ __forceinline__ void scst(float* p, float v){
  __hip_atomic_store(p, v, __ATOMIC_RELAXED, __HIP_MEMORY_SCOPE_AGENT);
}
__device__ __forceinline__ void scsti(int* p, int v){
  __hip_atomic_store(p, v, __ATOMIC_RELAXED, __HIP_MEMORY_SCOPE_AGENT);
}
__device__ __forceinline__ int lcldi(const int* p){
  return __hip_atomic_load((int*)p, __ATOMIC_RELAXED, __HIP_MEMORY_SCOPE_AGENT);
}

// hierarchical split barrier: relaxed bypass atomics, 256B-line-separated
// counters, no cache maintenance (writers drain vmcnt before arrive; readers
// use cached loads of write-once addresses).
__device__ __forceinline__ void gbar_arrive(int* grp_arr, int* grp_gen, int* root, int nb, int ph){
  const int gs = nb >> 4;
  const int g  = (int)blockIdx.x & 15;
  int a = __hip_atomic_fetch_add(grp_arr + g*64, 1, __ATOMIC_RELAXED, __HIP_MEMORY_SCOPE_AGENT) + 1;
  if (a == ph*gs){
    int r = __hip_atomic_fetch_add(root, 1, __ATOMIC_RELAXED, __HIP_MEMORY_SCOPE_AGENT) + 1;
    if (r == ph*NGRP){
      #pragma unroll
      for (int i = 0; i < NGRP; i++) scsti(grp_gen + i*64, ph);
    }
  }
}
__device__ __forceinline__ void gbar_wait(int* grp_gen, int ph){
  const int g = (int)blockIdx.x & 15;
  while (lcldi(grp_gen + g*64) < ph) __builtin_amdgcn_s_sleep(1);
}
// full barrier for multi-wave-store phases (__syncthreads drains each wave's vmcnt)
__device__ __forceinline__ void gbarH(int* gA, int* gG, int* gR, int nb, int ph){
  __syncthreads();
  if (threadIdx.x == 0){
    asm volatile("s_waitcnt vmcnt(0) lgkmcnt(0)" ::: "memory");
    gbar_arrive(gA, gG, gR, nb, ph);
    gbar_wait(gG, ph);
  }
  __syncthreads();
}

// ---------- demo transpose: demoT[l][b][d] = demo[0][b][l][d] ----------
__global__ __launch_bounds__(256) void demo_transpose_kernel(
    const float* __restrict__ demo, float* __restrict__ demoT)
{
  int idx = blockIdx.x*256 + threadIdx.x;
  if (idx < Ln*Bsz*Dn) {
    int d = idx & 127;
    int b = (idx >> 7) & 63;
    int l = idx >> 13;
    demoT[idx] = demo[((size_t)(b*Ln + l))*Dn + d];
  }
}

// ---------- generic tiled GEMM: C[M][N] = A[M][K] * B[N][K]^T + bias[n] ----------
__global__ __launch_bounds__(256) void gemm_nt_kernel(
    const float* __restrict__ A, int lda,
    const float* __restrict__ B, int ldb,
    const float* __restrict__ bias,
    float* __restrict__ C, int ldc, int K)
{
  __shared__ float As[64][17];
  __shared__ float Bs[64][17];
  const int m0 = blockIdx.x * 64;
  const int n0 = blockIdx.y * 64;
  const int tx = threadIdx.x & 15;
  const int ty = threadIdx.x >> 4;
  float acc[4][4] = {};
  for (int k0 = 0; k0 < K; k0 += 16) {
    #pragma unroll
    for (int i = 0; i < 4; i++) {
      int e = threadIdx.x + i*256;
      int r = e >> 4, c = e & 15;
      As[r][c] = A[(size_t)(m0 + r)*lda + k0 + c];
      Bs[r][c] = B[(size_t)(n0 + r)*ldb + k0 + c];
    }
    __syncthreads();
    #pragma unroll
    for (int kk = 0; kk < 16; kk++) {
      float a0 = As[ty*4+0][kk], a1 = As[ty*4+1][kk], a2 = As[ty*4+2][kk], a3 = As[ty*4+3][kk];
      float b0 = Bs[tx*4+0][kk], b1 = Bs[tx*4+1][kk], b2 = Bs[tx*4+2][kk], b3 = Bs[tx*4+3][kk];
      acc[0][0] += a0*b0; acc[0][1] += a0*b1; acc[0][2] += a0*b2; acc[0][3] += a0*b3;
      acc[1][0] += a1*b0; acc[1][1] += a1*b1; acc[1][2] += a1*b2; acc[1][3] += a1*b3;
      acc[2][0] += a2*b0; acc[2][1] += a2*b1; acc[2][2] += a2*b2; acc[2][3] += a2*b3;
      acc[3][0] += a3*b0; acc[3][1] += a3*b1; acc[3][2] += a3*b2; acc[3][3] += a3*b3;
    }
    __syncthreads();
  }
  #pragma unroll
  for (int i = 0; i < 4; i++) {
    #pragma unroll
    for (int j = 0; j < 4; j++) {
      int nn = n0 + tx*4 + j;
      float v = acc[i][j] + (bias ? bias[nn] : 0.0f);
      C[(size_t)(m0 + ty*4 + i)*ldc + nn] = v;
    }
  }
}

// ---------- head fold: M2 = out_W @ mid_W; bias2 = out_b + mid_b@out_W^T ----------
__global__ __launch_bounds__(512) void head_fold_kernel(
    const float* __restrict__ mid_W, const float* __restrict__ mid_b,
    const float* __restrict__ out_W, const float* __restrict__ out_b,
    float* __restrict__ M2, float* __restrict__ bias2)
{
  const int a = blockIdx.x;
  const int k = threadIdx.x;
  const float* ow = out_W + (size_t)a*Hn;
  float s = 0.f;
  #pragma unroll 4
  for (int n = 0; n < Hn; n++) s += ow[n]*mid_W[(size_t)n*Hn + k];
  M2[(size_t)a*Hn + k] = s;
  if (k == 0){
    float b2 = out_b[a];
    for (int n = 0; n < Hn; n++) b2 += ow[n]*mid_b[n];
    bias2[a] = b2;
  }
}

// ---------- q head: q[t][b][a] = hhist[t][b] . M2[a] + bias2[a] ----------
__global__ __launch_bounds__(256) void qhead_kernel(
    const float* __restrict__ hhist, const float* __restrict__ M2,
    const float* __restrict__ bias2, float* __restrict__ q)
{
  const int t = blockIdx.x;
  for (int p = threadIdx.x; p < Bsz*An; p += 256){
    int b = p / An, a = p % An;
    const float4* hv = (const float4*)(hhist + ((size_t)t*Bsz + b)*Hn);
    const float4* mv = (const float4*)(M2 + (size_t)a*Hn);
    float s = bias2[a];
    #pragma unroll 8
    for (int k = 0; k < Hn/4; k++){
      float4 H = hv[k], M = mv[k];
      s += H.x*M.x + H.y*M.y + H.z*M.z + H.w*M.w;
    }
    q[((size_t)(t*Bsz + b))*An + a] = s;
  }
}

// ---------- persistent fused encoder: merged single H-pass, deferred stores ----------
__global__ __launch_bounds__(512, 1) void enc_scan_kernel(
    const float* __restrict__ demoT,   // [Ln][Bsz][Dn]
    const float* __restrict__ Wih, const float* __restrict__ Whh,
    const float* __restrict__ bih, const float* __restrict__ bhh,
    const float* __restrict__ attn_W, const float* __restrict__ attn_b,
    const float* __restrict__ comb_W,
    float* __restrict__ hencR,         // [Ln][Bsz][Hn]
    float* __restrict__ attnp,         // [Bsz][Ln][Hn]
    float* __restrict__ CE,            // [Bsz][Ln][Hn]
    int* __restrict__ gA, int* __restrict__ gG, int* __restrict__ gR)
{
  const int bid  = blockIdx.x;
  const int tid  = threadIdx.x;
  const int lane = tid & 63;
  const int ks   = tid >> 6;
  const int n0   = bid*2;

  __shared__ float lds_whh[8][Hn];
  __shared__ float lds_wih[8][Dn];
  __shared__ float lds_atw[2][Hn];
  __shared__ float lds_cbw[2][Hn];
  __shared__ float red[8][12][Bsz];

  #pragma unroll
  for (int c = 0; c < 2; c++)
    #pragma unroll
    for (int g = 0; g < 4; g++){
      int r = c*4 + g;
      lds_whh[r][tid] = Whh[(size_t)(g*Hn + n0 + c)*Hn + tid];
      if (tid < Dn) lds_wih[r][tid] = Wih[(size_t)(g*Hn + n0 + c)*Dn + tid];
    }
  #pragma unroll
  for (int c = 0; c < 2; c++){
    lds_atw[c][tid] = attn_W[(size_t)(n0 + c)*Hn + tid];
    lds_cbw[c][tid] = comb_W[(size_t)(n0 + c)*(Hn + Dn) + tid];
  }
  float bsum[2][4];
  #pragma unroll
  for (int c = 0; c < 2; c++)
    #pragma unroll
    for (int g = 0; g < 4; g++){
      int r = g*Hn + n0 + c;
      bsum[c][g] = bih[r] + bhh[r];
    }
  const float ab[2] = { attn_b[n0], attn_b[n0+1] };
  float cr[2] = {0.f, 0.f};
  __syncthreads();

  for (int l = 0; l <= Ln; l++){
    float a[2][4] = {{0,0,0,0},{0,0,0,0}};
    float aa[2] = {0,0}, ac[2] = {0,0};
    if (l >= 1){
      const float4* hv = (const float4*)(hencR + ((size_t)(l-1)*Bsz + lane)*Hn) + ks*16;
      #pragma unroll 4
      for (int q = 0; q < 16; q++){
        float4 H = hv[q];
        #pragma unroll
        for (int c = 0; c < 2; c++){
          #pragma unroll
          for (int g = 0; g < 4; g++){
            float4 W = *(const float4*)&lds_whh[c*4+g][ks*64 + 4*q];
            a[c][g] += H.x*W.x + H.y*W.y + H.z*W.z + H.w*W.w;
          }
          float4 Aw = *(const float4*)&lds_atw[c][ks*64 + 4*q];
          aa[c] += H.x*Aw.x + H.y*Aw.y + H.z*Aw.z + H.w*Aw.w;
          float4 Cw = *(const float4*)&lds_cbw[c][ks*64 + 4*q];
          ac[c] += H.x*Cw.x + H.y*Cw.y + H.z*Cw.z + H.w*Cw.w;
        }
      }
    }
    if (l < Ln){
      const float4* dv = (const float4*)(demoT + ((size_t)l*Bsz + lane)*Dn) + ks*4;
      #pragma unroll
      for (int q = 0; q < 4; q++){
        float4 V = dv[q];
        #pragma unroll
        for (int c = 0; c < 2; c++)
          #pragma unroll
          for (int g = 0; g < 4; g++){
            float4 W = *(const float4*)&lds_wih[c*4+g][ks*16 + 4*q];
            a[c][g] += V.x*W.x + V.y*W.y + V.z*W.z + V.w*W.w;
          }
      }
    }
    #pragma unroll
    for (int c = 0; c < 2; c++){
      #pragma unroll
      for (int g = 0; g < 4; g++) red[ks][c*4+g][lane] = a[c][g];
      red[ks][8+c][lane]  = aa[c];
      red[ks][10+c][lane] = ac[c];
    }
    __syncthreads();
    // recurrence-critical: cell + h store
    if (tid < Bsz && l < Ln){
      int b = tid;
      #pragma unroll
      for (int c = 0; c < 2; c++){
        float g0 = bsum[c][0], g1 = bsum[c][1], g2 = bsum[c][2], g3 = bsum[c][3];
        #pragma unroll
        for (int k = 0; k < 8; k++){
          g0 += red[k][c*4+0][b]; g1 += red[k][c*4+1][b];
          g2 += red[k][c*4+2][b]; g3 += red[k][c*4+3][b];
        }
        float ii = sigf(g0), ff = sigf(g1), gg = tanhf(g2), oo = sigf(g3);
        float cn = ff*cr[c] + ii*gg;
        float hn = oo*tanhf(cn);
        cr[c] = cn;
        scst(hencR + ((size_t)l*Bsz + b)*Hn + n0 + c, hn);
      }
    }
    // early arrive: h written only by wave 0; wave-local vmcnt drain suffices
    if (l < Ln && tid == 0){
      asm volatile("s_waitcnt vmcnt(0)" ::: "memory");
      gbar_arrive(gA, gG, gR, (int)gridDim.x, l+1);
    }
    // off-critical-path: attnp/CE stores for step l-1 (reduced from red slots)
    if (tid < Bsz && l >= 1){
      int b = tid;
      #pragma unroll
      for (int c = 0; c < 2; c++){
        float av = ab[c], cv = 0.f;
        #pragma unroll
        for (int k = 0; k < 8; k++){ av += red[k][8+c][b]; cv += red[k][10+c][b]; }
        scst(attnp + ((size_t)(b*Ln + (l-1)))*Hn + n0 + c, av);
        scst(CE    + ((size_t)(b*Ln + (l-1)))*Hn + n0 + c, cv);
      }
    }
    if (l < Ln){
      if (tid == 0) gbar_wait(gG, l+1);
      __syncthreads();
    }
  }
}

// ---------- persistent decoder: flash-split attn + on-the-fly x assembly ----------
__global__ __launch_bounds__(512, 1) void dec_scan_kernel(
    const float* __restrict__ h0, const float* __restrict__ c0,
    const float* __restrict__ attnp,   // [Bsz][Ln][Hn]
    const float* __restrict__ CE,      // [Bsz][Ln][Hn]
    const float* __restrict__ preobs,  // [Tn*Bsz][Hn]
    const int*   __restrict__ dlen,
    const float* __restrict__ lstm_Wih, const float* __restrict__ lstm_Whh,
    const float* __restrict__ lstm_bih, const float* __restrict__ lstm_bhh,
    const float* __restrict__ comb_b,
    float* __restrict__ app,           // [Tn][2][Bsz][Hn] write-once
    float* __restrict__ dmax,          // [Tn][2][Bsz]
    float* __restrict__ dden,          // [Tn][2][Bsz]
    float* __restrict__ hhist,         // [Tn][Bsz][Hn] write-once
    float* __restrict__ outp,
    int* __restrict__ gA, int* __restrict__ gG, int* __restrict__ gR)
{
  const int bid  = blockIdx.x;
  const int tid  = threadIdx.x;
  const int lane = tid & 63;
  const int ks   = tid >> 6;
  const int n0   = bid*2;

  __shared__ float lds_wi[8][Hn];
  __shared__ float lds_wh[8][Hn];
  __shared__ float hs[Hn];
  __shared__ float cbs[Hn];
  __shared__ float sls[64];
  __shared__ float wls[64];
  __shared__ float red[8][8][Bsz];

  #pragma unroll
  for (int c = 0; c < 2; c++)
    #pragma unroll
    for (int g = 0; g < 4; g++){
      int r = c*4 + g;
      lds_wi[r][tid] = lstm_Wih[(size_t)(g*Hn + n0 + c)*Hn + tid];
      lds_wh[r][tid] = lstm_Whh[(size_t)(g*Hn + n0 + c)*Hn + tid];
    }
  cbs[tid] = comb_b[tid];
  float bs[2][4];
  #pragma unroll
  for (int c = 0; c < 2; c++)
    #pragma unroll
    for (int g = 0; g < 4; g++){
      int r = g*Hn + n0 + c;
      bs[c][g] = lstm_bih[r] + lstm_bhh[r];
    }
  float cr[2] = {0.f, 0.f};
  int ph = 0;
  __syncthreads();

  const int batn = bid & 63;      // attn role: batch
  const int qq   = bid >> 6;      // attn role: l-chunk (0/1), valid when bid<128

  for (int t = 0; t < Tn; t++){
    const float* hprev_all = (t == 0) ? h0 : (hhist + (size_t)(t-1)*Bsz*Hn);

    // ================= Phase A =================
    if (bid < 128) hs[tid] = hprev_all[(size_t)batn*Hn + tid];

    // all blocks: Whh @ h(t-1) partial (own 2 cols), kept in VGPRs across barrier
    float hpa[2][4] = {{0,0,0,0},{0,0,0,0}};
    {
      const float4* hv = (const float4*)(hprev_all + (size_t)lane*Hn) + ks*16;
      #pragma unroll 4
      for (int q = 0; q < 16; q++){
        float4 H = hv[q];
        #pragma unroll
        for (int c = 0; c < 2; c++)
          #pragma unroll
          for (int g = 0; g < 4; g++){
            float4 W = *(const float4*)&lds_wh[c*4+g][ks*64 + 4*q];
            hpa[c][g] += H.x*W.x + H.y*W.y + H.z*W.z + H.w*W.w;
          }
      }
    }

    if (bid < 128){
      const int b = batn;
      const int l0 = qq*50;
      __syncthreads();
      const int len = dlen[b];
      const int li = tid >> 3, sub = tid & 7;
      // scores for 50 l-values: 8 threads per l
      float s = -1e30f;
      if (li < 50){
        const float4* ap = (const float4*)(attnp + ((size_t)(b*Ln + l0 + li))*Hn) + sub*16;
        const float4* hv2 = (const float4*)hs + sub*16;
        float acc = 0.f;
        #pragma unroll
        for (int k = 0; k < 16; k++){
          float4 A = ap[k], H = hv2[k];
          acc += A.x*H.x + A.y*H.y + A.z*H.z + A.w*H.w;
        }
        acc += __shfl_xor(acc, 1);
        acc += __shfl_xor(acc, 2);
        acc += __shfl_xor(acc, 4);
        s = acc;
      }
      if (sub == 0) sls[li] = (li < 50 && (l0 + li) < len) ? s*0.1f : -1e30f;
      __syncthreads();
      // local softmax pieces (max / exp / den) over the 50-chunk
      if (tid < 64){
        float v = sls[tid];
        float m = v;
        #pragma unroll
        for (int off = 1; off < 64; off <<= 1) m = fmaxf(m, __shfl_xor(m, off));
        float w = expf(v - m);           // masked -> 0 (or garbage if chunk fully masked; killed by combine)
        wls[tid] = w;
        float dsum = w;
        #pragma unroll
        for (int off = 1; off < 64; off <<= 1) dsum += __shfl_xor(dsum, off);
        if (tid == 0){
          scst(dmax + ((size_t)t*2 + qq)*Bsz + b, m);
          scst(dden + ((size_t)t*2 + qq)*Bsz + b, dsum);
        }
      }
      __syncthreads();
      // partial applied: app[n] = sum_{l in chunk} w_l * CE[b][l][n] (uniform 50 iters)
      {
        const int n = tid;
        const float* ceb = CE + ((size_t)(b*Ln + l0))*Hn + n;
        float apv = 0.f;
        #pragma unroll 5
        for (int l2 = 0; l2 < 50; l2++) apv += wls[l2]*ceb[(size_t)l2*Hn];
        scst(app + (((size_t)t*2 + qq)*Bsz + b)*Hn + n, apv);
      }
    }
    gbarH(gA, gG, gR, (int)gridDim.x, ++ph);   // app/dmax/dden by many waves -> full barrier

    // ================= Phase C: assemble x on the fly; gates; cell =================
    {
      const size_t i0 = ((size_t)t*2 + 0)*Bsz + lane;
      const size_t i1 = ((size_t)t*2 + 1)*Bsz + lane;
      float m0 = dmax[i0], m1 = dmax[i1], d0v = dden[i0], d1v = dden[i1];
      float M  = fmaxf(m0, m1);
      float e0 = expf(m0 - M), e1 = expf(m1 - M);
      float D  = e0*d0v + e1*d1v;
      float s0 = e0/D, s1 = e1/D;
      const float4* a0v = (const float4*)(app + i0*Hn) + ks*16;
      const float4* a1v = (const float4*)(app + i1*Hn) + ks*16;
      const float4* pv  = (const float4*)(preobs + ((size_t)t*Bsz + lane)*Hn) + ks*16;
      #pragma unroll 4
      for (int q = 0; q < 16; q++){
        float4 A0 = a0v[q], A1 = a1v[q], P = pv[q];
        float4 CB = *(const float4*)&cbs[ks*64 + 4*q];
        float4 X;
        X.x = fmaxf(s0*A0.x + s1*A1.x + P.x + CB.x, 0.f);
        X.y = fmaxf(s0*A0.y + s1*A1.y + P.y + CB.y, 0.f);
        X.z = fmaxf(s0*A0.z + s1*A1.z + P.z + CB.z, 0.f);
        X.w = fmaxf(s0*A0.w + s1*A1.w + P.w + CB.w, 0.f);
        #pragma unroll
        for (int c = 0; c < 2; c++)
          #pragma unroll
          for (int g = 0; g < 4; g++){
            float4 W = *(const float4*)&lds_wi[c*4+g][ks*64 + 4*q];
            hpa[c][g] += X.x*W.x + X.y*W.y + X.z*W.z + X.w*W.w;
          }
      }
      #pragma unroll
      for (int c = 0; c < 2; c++)
        #pragma unroll
        for (int g = 0; g < 4; g++) red[ks][c*4+g][lane] = hpa[c][g];
      __syncthreads();
      if (tid < Bsz){
        int b = tid;
        #pragma unroll
        for (int c = 0; c < 2; c++){
          int n = n0 + c;
          if (t == 0) cr[c] = c0[(size_t)b*Hn + n];
          float g0 = bs[c][0], g1 = bs[c][1], g2 = bs[c][2], g3 = bs[c][3];
          #pragma unroll
          for (int k = 0; k < 8; k++){
            g0 += red[k][c*4+0][b]; g1 += red[k][c*4+1][b];
            g2 += red[k][c*4+2][b]; g3 += red[k][c*4+3][b];
          }
          float ii = sigf(g0), ff = sigf(g1), gg = tanhf(g2), oo = sigf(g3);
          float cn = ff*cr[c] + ii*gg;
          float hn = oo*tanhf(cn);
          cr[c] = cn;
          scst(hhist + ((size_t)t*Bsz + b)*Hn + n, hn);
          if (t == Tn - 1){
            outp[Tn*Bsz*An + (size_t)b*Hn + n]           = hn;
            outp[Tn*Bsz*An + Bsz*Hn + (size_t)b*Hn + n]  = cn;
          }
        }
      }
      // h written only by wave 0 -> wave-local drain + early arrive
      if (t < Tn - 1){
        if (tid == 0){
          asm volatile("s_waitcnt vmcnt(0)" ::: "memory");
          gbar_arrive(gA, gG, gR, (int)gridDim.x, ph+1);
          gbar_wait(gG, ph+1);
        }
        ph++;
        __syncthreads();
      }
    }
  }
}

extern "C" void kernel_launch(void* const* d_in, const int* in_sizes, int n_in,
                              void* d_out, int out_size, void* d_ws, size_t ws_size,
                              hipStream_t stream) {
  (void)in_sizes; (void)n_in; (void)out_size; (void)ws_size;
  const float* state    = (const float*)d_in[0];
  const float* demo     = (const float*)d_in[1];
  const int*   dlen     = (const int*)  d_in[2];
  const float* h0       = (const float*)d_in[5];
  const float* c0       = (const float*)d_in[6];
  const float* enc_Wih  = (const float*)d_in[7];
  const float* enc_Whh  = (const float*)d_in[8];
  const float* enc_bih  = (const float*)d_in[9];
  const float* enc_bhh  = (const float*)d_in[10];
  const float* attn_W   = (const float*)d_in[11];
  const float* attn_b   = (const float*)d_in[12];
  const float* comb_W   = (const float*)d_in[13];
  const float* comb_b   = (const float*)d_in[14];
  const float* lstm_Wih = (const float*)d_in[15];
  const float* lstm_Whh = (const float*)d_in[16];
  const float* lstm_bih = (const float*)d_in[17];
  const float* lstm_bhh = (const float*)d_in[18];
  const float* mid_W    = (const float*)d_in[19];
  const float* mid_b    = (const float*)d_in[20];
  const float* out_W    = (const float*)d_in[21];
  const float* out_b    = (const float*)d_in[22];
  float* ws   = (float*)d_ws;
  float* qout = (float*)d_out;

  // workspace layout (f32 words), ~60 MB
  float* attnp  = ws + 0;         // 3,276,800  [B][L][H]
  float* CE     = ws + 3276800;   // 3,276,800  [B][L][H]
  float* preobs = ws + 6553600;   // 2,097,152  [T*B][H]
  float* region = ws + 8650752;   // 6,307,840 shared region:
  float* demoT  = region;                   // enc: 819,200   [L][B][D]
  float* hencR  = region + 819200;          // enc: 3,276,800 [L][B][H]
  float* hhist  = region;                   // dec: 2,097,152 [T][B][H]
  float* app    = region + 2097152;         // dec: 4,194,304 [T][2][B][H]
  float* dmax   = region + 6291456;         // dec: 8,192     [T][2][B]
  float* dden   = region + 6299648;         // dec: 8,192
  int*   barB   = (int*)(ws + 14958592);    // 4224 ints
  int* encA = barB;          int* encG = barB + 1024; int* encR = barB + 2048;
  int* decA = barB + 2112;   int* decG = barB + 3136; int* decR = barB + 4160;
  float* M2    = ws + 14962816;   // 9,216  [An][Hn]
  float* bias2 = ws + 14972032;   // 64

  hipMemsetAsync((void*)barB, 0, 4224*4, stream);

  demo_transpose_kernel<<<3200, 256, 0, stream>>>(demo, demoT);

  head_fold_kernel<<<An, 512, 0, stream>>>(mid_W, mid_b, out_W, out_b, M2, bias2);

  // preobs[(t,b)][n] = state[t,b,:] . comb_W[n, 512:640]
  gemm_nt_kernel<<<dim3(Tn*Bsz/64, Hn/64), 256, 0, stream>>>(
      state, Dn, comb_W + Hn, Hn + Dn, nullptr, preobs, Hn, Dn);

  enc_scan_kernel<<<256, 512, 0, stream>>>(
      demoT, enc_Wih, enc_Whh, enc_bih, enc_bhh, attn_W, attn_b, comb_W,
      hencR, attnp, CE, encA, encG, encR);

  dec_scan_kernel<<<256, 512, 0, stream>>>(
      h0, c0, attnp, CE, preobs, dlen, lstm_Wih, lstm_Whh, lstm_bih, lstm_bhh,
      comb_b, app, dmax, dden, hhist, qout, decA, decG, decR);

  // q = hhist @ M2^T + bias2
  qhead_kernel<<<Tn, 256, 0, stream>>>(hhist, M2, bias2, qout);
}

// Round 11
// 2834.533 us; speedup vs baseline: 1.2059x; 1.1211x over previous
//
#include <hip/hip_runtime.h>
#include <math.h>

#define Bsz 64
#define Tn 64
#define Ln 100
#define Dn 128
#define An 18
#define Hn 512
#define NGRP 16

__device__ __forceinline__ float sigf(float x){ return 1.0f/(1.0f+expf(-x)); }

__device__ __forceinline__ void scst(float* p, float v){
  __hip_atomic_store(p, v, __ATOMIC_RELAXED, __HIP_MEMORY_SCOPE_AGENT);
}
__device__ __forceinline__ void scsti(int* p, int v){
  __hip_atomic_store(p, v, __ATOMIC_RELAXED, __HIP_MEMORY_SCOPE_AGENT);
}
__device__ __forceinline__ int lcldi(const int* p){
  return __hip_atomic_load((int*)p, __ATOMIC_RELAXED, __HIP_MEMORY_SCOPE_AGENT);
}

// Hierarchical grid barrier (16 groups x 16 blocks, 256B-line-separated
// counters, monotonic phases). Writers drain vmcnt before arrival
// (__syncthreads drains each wave); readers use cached loads of WRITE-ONCE,
// NON-ALIASED addresses -> no cache maintenance needed. (De-aliasing is the
// correctness invariant: a bypass store never rewrites an address another
// XCD may hold cached with a DIFFERENT value.)
__device__ __forceinline__ void gbar_arrive(int* grp_arr, int* grp_gen, int* root, int nb, int ph){
  const int gs = nb >> 4;
  const int g  = (int)blockIdx.x & 15;
  int a = __hip_atomic_fetch_add(grp_arr + g*64, 1, __ATOMIC_RELAXED, __HIP_MEMORY_SCOPE_AGENT) + 1;
  if (a == ph*gs){
    int r = __hip_atomic_fetch_add(root, 1, __ATOMIC_RELAXED, __HIP_MEMORY_SCOPE_AGENT) + 1;
    if (r == ph*NGRP){
      #pragma unroll
      for (int i = 0; i < NGRP; i++) scsti(grp_gen + i*64, ph);
    }
  }
}
__device__ __forceinline__ void gbar_wait(int* grp_gen, int ph){
  const int g = (int)blockIdx.x & 15;
  while (lcldi(grp_gen + g*64) < ph) __builtin_amdgcn_s_sleep(1);
}
__device__ __forceinline__ void gbarH(int* gA, int* gG, int* gR, int nb, int ph){
  __syncthreads();
  if (threadIdx.x == 0){
    asm volatile("s_waitcnt vmcnt(0) lgkmcnt(0)" ::: "memory");
    gbar_arrive(gA, gG, gR, nb, ph);
    gbar_wait(gG, ph);
  }
  __syncthreads();
}

// ---------- demo transpose: demoT[l][b][d] = demo[0][b][l][d] ----------
__global__ __launch_bounds__(256) void demo_transpose_kernel(
    const float* __restrict__ demo, float* __restrict__ demoT)
{
  int idx = blockIdx.x*256 + threadIdx.x;
  if (idx < Ln*Bsz*Dn) {
    int d = idx & 127;
    int b = (idx >> 7) & 63;
    int l = idx >> 13;
    demoT[idx] = demo[((size_t)(b*Ln + l))*Dn + d];
  }
}

// ---------- generic tiled GEMM: C[M][N] = A[M][K] * B[N][K]^T + bias[n] ----------
__global__ __launch_bounds__(256) void gemm_nt_kernel(
    const float* __restrict__ A, int lda,
    const float* __restrict__ B, int ldb,
    const float* __restrict__ bias,
    float* __restrict__ C, int ldc, int K)
{
  __shared__ float As[64][17];
  __shared__ float Bs[64][17];
  const int m0 = blockIdx.x * 64;
  const int n0 = blockIdx.y * 64;
  const int tx = threadIdx.x & 15;
  const int ty = threadIdx.x >> 4;
  float acc[4][4] = {};
  for (int k0 = 0; k0 < K; k0 += 16) {
    #pragma unroll
    for (int i = 0; i < 4; i++) {
      int e = threadIdx.x + i*256;
      int r = e >> 4, c = e & 15;
      As[r][c] = A[(size_t)(m0 + r)*lda + k0 + c];
      Bs[r][c] = B[(size_t)(n0 + r)*ldb + k0 + c];
    }
    __syncthreads();
    #pragma unroll
    for (int kk = 0; kk < 16; kk++) {
      float a0 = As[ty*4+0][kk], a1 = As[ty*4+1][kk], a2 = As[ty*4+2][kk], a3 = As[ty*4+3][kk];
      float b0 = Bs[tx*4+0][kk], b1 = Bs[tx*4+1][kk], b2 = Bs[tx*4+2][kk], b3 = Bs[tx*4+3][kk];
      acc[0][0] += a0*b0; acc[0][1] += a0*b1; acc[0][2] += a0*b2; acc[0][3] += a0*b3;
      acc[1][0] += a1*b0; acc[1][1] += a1*b1; acc[1][2] += a1*b2; acc[1][3] += a1*b3;
      acc[2][0] += a2*b0; acc[2][1] += a2*b1; acc[2][2] += a2*b2; acc[2][3] += a2*b3;
      acc[3][0] += a3*b0; acc[3][1] += a3*b1; acc[3][2] += a3*b2; acc[3][3] += a3*b3;
    }
    __syncthreads();
  }
  #pragma unroll
  for (int i = 0; i < 4; i++) {
    #pragma unroll
    for (int j = 0; j < 4; j++) {
      int nn = n0 + tx*4 + j;
      float v = acc[i][j] + (bias ? bias[nn] : 0.0f);
      C[(size_t)(m0 + ty*4 + i)*ldc + nn] = v;
    }
  }
}

// ---------- head fold: M2 = out_W @ mid_W; bias2 = out_b + mid_b@out_W^T ----------
__global__ __launch_bounds__(512) void head_fold_kernel(
    const float* __restrict__ mid_W, const float* __restrict__ mid_b,
    const float* __restrict__ out_W, const float* __restrict__ out_b,
    float* __restrict__ M2, float* __restrict__ bias2)
{
  const int a = blockIdx.x;
  const int k = threadIdx.x;
  const float* ow = out_W + (size_t)a*Hn;
  float s = 0.f;
  #pragma unroll 4
  for (int n = 0; n < Hn; n++) s += ow[n]*mid_W[(size_t)n*Hn + k];
  M2[(size_t)a*Hn + k] = s;
  if (k == 0){
    float b2 = out_b[a];
    for (int n = 0; n < Hn; n++) b2 += ow[n]*mid_b[n];
    bias2[a] = b2;
  }
}

// ---------- q head: q[t][b][a] = hhist[t][b] . M2[a] + bias2[a] ----------
__global__ __launch_bounds__(256) void qhead_kernel(
    const float* __restrict__ hhist, const float* __restrict__ M2,
    const float* __restrict__ bias2, float* __restrict__ q)
{
  const int t = blockIdx.x;
  for (int p = threadIdx.x; p < Bsz*An; p += 256){
    int b = p / An, a = p % An;
    const float4* hv = (const float4*)(hhist + ((size_t)t*Bsz + b)*Hn);
    const float4* mv = (const float4*)(M2 + (size_t)a*Hn);
    float s = bias2[a];
    #pragma unroll 8
    for (int k = 0; k < Hn/4; k++){
      float4 H = hv[k], M = mv[k];
      s += H.x*M.x + H.y*M.y + H.z*M.z + H.w*M.w;
    }
    q[((size_t)(t*Bsz + b))*An + a] = s;
  }
}

// ---------- persistent fused encoder: LDS weights, merged pass ----------
__global__ __launch_bounds__(512, 1) void enc_scan_kernel(
    const float* __restrict__ demoT,   // [Ln][Bsz][Dn]
    const float* __restrict__ Wih, const float* __restrict__ Whh,
    const float* __restrict__ bih, const float* __restrict__ bhh,
    const float* __restrict__ attn_W, const float* __restrict__ attn_b,
    const float* __restrict__ comb_W,
    float* __restrict__ hencR,         // [Ln][Bsz][Hn]  write-once, non-aliased
    float* __restrict__ attnp,         // [Bsz][Ln][Hn]
    float* __restrict__ CE,            // [Bsz][Ln][Hn] (+pad)
    int* __restrict__ gA, int* __restrict__ gG, int* __restrict__ gR)
{
  const int bid  = blockIdx.x;
  const int tid  = threadIdx.x;
  const int lane = tid & 63;
  const int ks   = tid >> 6;          // 0..7
  const int n0   = bid*2;

  __shared__ float lds_whh[8][Hn];
  __shared__ float lds_wih[8][Dn];
  __shared__ float lds_atw[2][Hn];
  __shared__ float lds_cbw[2][Hn];
  __shared__ float red[8][12][Bsz];

  #pragma unroll
  for (int c = 0; c < 2; c++)
    #pragma unroll
    for (int g = 0; g < 4; g++){
      int r = c*4 + g;
      lds_whh[r][tid] = Whh[(size_t)(g*Hn + n0 + c)*Hn + tid];
      if (tid < Dn) lds_wih[r][tid] = Wih[(size_t)(g*Hn + n0 + c)*Dn + tid];
    }
  #pragma unroll
  for (int c = 0; c < 2; c++){
    lds_atw[c][tid] = attn_W[(size_t)(n0 + c)*Hn + tid];
    lds_cbw[c][tid] = comb_W[(size_t)(n0 + c)*(Hn + Dn) + tid];
  }
  float bsum[2][4];
  #pragma unroll
  for (int c = 0; c < 2; c++)
    #pragma unroll
    for (int g = 0; g < 4; g++){
      int r = g*Hn + n0 + c;
      bsum[c][g] = bih[r] + bhh[r];
    }
  const float ab[2] = { attn_b[n0], attn_b[n0+1] };
  float cr[2] = {0.f, 0.f};
  __syncthreads();

  for (int l = 0; l <= Ln; l++){
    float a[2][4] = {{0,0,0,0},{0,0,0,0}};
    float aa[2] = {0,0}, ac[2] = {0,0};
    if (l >= 1){
      const float4* hv = (const float4*)(hencR + ((size_t)(l-1)*Bsz + lane)*Hn) + ks*16;
      #pragma unroll 4
      for (int q = 0; q < 16; q++){
        float4 H = hv[q];
        #pragma unroll
        for (int c = 0; c < 2; c++){
          #pragma unroll
          for (int g = 0; g < 4; g++){
            float4 W = *(const float4*)&lds_whh[c*4+g][ks*64 + 4*q];
            a[c][g] += H.x*W.x + H.y*W.y + H.z*W.z + H.w*W.w;
          }
          float4 Aw = *(const float4*)&lds_atw[c][ks*64 + 4*q];
          aa[c] += H.x*Aw.x + H.y*Aw.y + H.z*Aw.z + H.w*Aw.w;
          float4 Cw = *(const float4*)&lds_cbw[c][ks*64 + 4*q];
          ac[c] += H.x*Cw.x + H.y*Cw.y + H.z*Cw.z + H.w*Cw.w;
        }
      }
    }
    if (l < Ln){
      const float4* dv = (const float4*)(demoT + ((size_t)l*Bsz + lane)*Dn) + ks*4;
      #pragma unroll
      for (int q = 0; q < 4; q++){
        float4 V = dv[q];
        #pragma unroll
        for (int c = 0; c < 2; c++)
          #pragma unroll
          for (int g = 0; g < 4; g++){
            float4 W = *(const float4*)&lds_wih[c*4+g][ks*16 + 4*q];
            a[c][g] += V.x*W.x + V.y*W.y + V.z*W.z + V.w*W.w;
          }
      }
    }
    #pragma unroll
    for (int c = 0; c < 2; c++){
      #pragma unroll
      for (int g = 0; g < 4; g++) red[ks][c*4+g][lane] = a[c][g];
      red[ks][8+c][lane]  = aa[c];
      red[ks][10+c][lane] = ac[c];
    }
    __syncthreads();
    if (tid < Bsz){
      int b = tid;
      if (l < Ln){
        #pragma unroll
        for (int c = 0; c < 2; c++){
          float g0 = bsum[c][0], g1 = bsum[c][1], g2 = bsum[c][2], g3 = bsum[c][3];
          #pragma unroll
          for (int k = 0; k < 8; k++){
            g0 += red[k][c*4+0][b]; g1 += red[k][c*4+1][b];
            g2 += red[k][c*4+2][b]; g3 += red[k][c*4+3][b];
          }
          float ii = sigf(g0), ff = sigf(g1), gg = tanhf(g2), oo = sigf(g3);
          float cn = ff*cr[c] + ii*gg;
          float hn = oo*tanhf(cn);
          cr[c] = cn;
          scst(hencR + ((size_t)l*Bsz + b)*Hn + n0 + c, hn);
        }
      }
      if (l >= 1){
        #pragma unroll
        for (int c = 0; c < 2; c++){
          float av = ab[c], cv = 0.f;
          #pragma unroll
          for (int k = 0; k < 8; k++){ av += red[k][8+c][b]; cv += red[k][10+c][b]; }
          scst(attnp + ((size_t)(b*Ln + (l-1)))*Hn + n0 + c, av);
          scst(CE    + ((size_t)(b*Ln + (l-1)))*Hn + n0 + c, cv);
        }
      }
    }
    if (l < Ln) gbarH(gA, gG, gR, (int)gridDim.x, l+1);
  }
}

// ---------- persistent decoder: LDS weights, 2 phases/step ----------
__global__ __launch_bounds__(512, 1) void dec_scan_kernel(
    const float* __restrict__ h0, const float* __restrict__ c0,
    const float* __restrict__ attnp,   // [Bsz][Ln][Hn]
    const float* __restrict__ CE,      // [Bsz][Ln][Hn] (+pad, over-read x0 safe)
    const float* __restrict__ preobs,  // [Tn*Bsz][Hn]
    const int*   __restrict__ dlen,
    const float* __restrict__ lstm_Wih, const float* __restrict__ lstm_Whh,
    const float* __restrict__ lstm_bih, const float* __restrict__ lstm_bhh,
    const float* __restrict__ comb_b,
    float* __restrict__ xrow,          // [Tn][Bsz][Hn]  write-once, non-aliased
    float* __restrict__ hhist,         // [Tn][Bsz][Hn]  write-once, non-aliased
    float* __restrict__ outp,
    int* __restrict__ gA, int* __restrict__ gG, int* __restrict__ gR)
{
  const int bid  = blockIdx.x;
  const int tid  = threadIdx.x;
  const int lane = tid & 63;
  const int ks   = tid >> 6;          // 0..7
  const int n0   = bid*2;

  __shared__ float lds_wi[8][Hn];
  __shared__ float lds_wh[8][Hn];
  __shared__ float hs[Hn];
  __shared__ float wls[128];
  __shared__ float mx_s, sum_s;
  __shared__ float red[8][8][Bsz];

  #pragma unroll
  for (int c = 0; c < 2; c++)
    #pragma unroll
    for (int g = 0; g < 4; g++){
      int r = c*4 + g;
      lds_wi[r][tid] = lstm_Wih[(size_t)(g*Hn + n0 + c)*Hn + tid];
      lds_wh[r][tid] = lstm_Whh[(size_t)(g*Hn + n0 + c)*Hn + tid];
    }
  float bs[2][4];
  #pragma unroll
  for (int c = 0; c < 2; c++)
    #pragma unroll
    for (int g = 0; g < 4; g++){
      int r = g*Hn + n0 + c;
      bs[c][g] = lstm_bih[r] + lstm_bhh[r];
    }
  float cr[2] = {0.f, 0.f};
  // hoisted: t-invariant attention length for this block's batch
  int len = 0, lenr = 0;
  if (bid < Bsz){ len = dlen[bid]; lenr = (len + 7) & ~7; }
  int ph = 0;
  __syncthreads();

  for (int t = 0; t < Tn; t++){
    const float* hprev_all = (t == 0) ? h0 : (hhist + (size_t)(t-1)*Bsz*Hn);

    // ============ Phase 1: attention (blocks 0..63) + Whh@h partial (ALL) ============
    if (bid < Bsz){
      const int b = bid;
      hs[tid] = hprev_all[(size_t)b*Hn + tid];
      if (tid >= 100 && tid < 128) wls[tid] = -1e30f;
      __syncthreads();
      if (tid < 400){
        int l = tid >> 2, kh = tid & 3;
        const float4* ap = (const float4*)(attnp + ((size_t)(b*Ln + l))*Hn) + kh*32;
        const float4* hv = (const float4*)hs + kh*32;
        float s = 0.f;
        #pragma unroll 8
        for (int k = 0; k < 32; k++){
          float4 A = ap[k], H = hv[k];
          s += A.x*H.x + A.y*H.y + A.z*H.z + A.w*H.w;
        }
        s += __shfl_xor(s, 1);
        s += __shfl_xor(s, 2);
        if (kh == 0) wls[l] = (l < len) ? s*0.1f : -1e30f;
      }
      __syncthreads();
      if (tid < 64){
        float v = fmaxf(wls[tid], wls[tid+64]);
        for (int off = 1; off < 64; off <<= 1) v = fmaxf(v, __shfl_xor(v, off));
        if (tid == 0) mx_s = v;
      }
      __syncthreads();
      float mx = mx_s;
      if (tid < 64){
        float e0 = (wls[tid]    > -1e29f) ? expf(wls[tid]    - mx) : 0.f;
        float e1 = (wls[tid+64] > -1e29f) ? expf(wls[tid+64] - mx) : 0.f;
        wls[tid] = e0; wls[tid+64] = e1;   // exact 0.0 beyond len (incl. 100..127)
        float v = e0 + e1;
        for (int off = 1; off < 64; off <<= 1) v += __shfl_xor(v, off);
        if (tid == 0) sum_s = v;
      }
      __syncthreads();
      float inv = 1.0f / sum_s;
      {
        int n = tid;
        const float* cb = CE + (size_t)b*Ln*Hn + n;
        float acc = 0.f;
        #pragma unroll 8
        for (int l2 = 0; l2 < lenr; ++l2) acc += cb[(size_t)l2*Hn]*wls[l2]; // wls==0 pads
        float v = acc*inv + preobs[((size_t)(t*Bsz + b))*Hn + n] + comb_b[n];
        scst(xrow + ((size_t)t*Bsz + b)*Hn + n, fmaxf(v, 0.f));
      }
    }
    // all blocks: Whh @ h(t-1) partial for own 2 columns; kept in VGPRs across barrier
    float hpa[2][4] = {{0,0,0,0},{0,0,0,0}};
    {
      const float4* hv = (const float4*)(hprev_all + (size_t)lane*Hn) + ks*16;
      #pragma unroll 4
      for (int q = 0; q < 16; q++){
        float4 H = hv[q];
        #pragma unroll
        for (int c = 0; c < 2; c++)
          #pragma unroll
          for (int g = 0; g < 4; g++){
            float4 W = *(const float4*)&lds_wh[c*4+g][ks*64 + 4*q];
            hpa[c][g] += H.x*W.x + H.y*W.y + H.z*W.z + H.w*W.w;
          }
      }
    }
    gbarH(gA, gG, gR, (int)gridDim.x, ++ph);

    // ============ Phase 2: += Wih@x; reduce; cell ============
    {
      const float4* xv = (const float4*)(xrow + ((size_t)t*Bsz + lane)*Hn) + ks*16;
      #pragma unroll 4
      for (int q = 0; q < 16; q++){
        float4 X = xv[q];
        #pragma unroll
        for (int c = 0; c < 2; c++)
          #pragma unroll
          for (int g = 0; g < 4; g++){
            float4 W = *(const float4*)&lds_wi[c*4+g][ks*64 + 4*q];
            hpa[c][g] += X.x*W.x + X.y*W.y + X.z*W.z + X.w*W.w;
          }
      }
      #pragma unroll
      for (int c = 0; c < 2; c++)
        #pragma unroll
        for (int g = 0; g < 4; g++) red[ks][c*4+g][lane] = hpa[c][g];
      __syncthreads();
      if (tid < Bsz){
        int b = tid;
        #pragma unroll
        for (int c = 0; c < 2; c++){
          int n = n0 + c;
          if (t == 0) cr[c] = c0[(size_t)b*Hn + n];
          float g0 = bs[c][0], g1 = bs[c][1], g2 = bs[c][2], g3 = bs[c][3];
          #pragma unroll
          for (int k = 0; k < 8; k++){
            g0 += red[k][c*4+0][b]; g1 += red[k][c*4+1][b];
            g2 += red[k][c*4+2][b]; g3 += red[k][c*4+3][b];
          }
          float ii = sigf(g0), ff = sigf(g1), gg = tanhf(g2), oo = sigf(g3);
          float cn = ff*cr[c] + ii*gg;
          float hn = oo*tanhf(cn);
          cr[c] = cn;
          scst(hhist + ((size_t)t*Bsz + b)*Hn + n, hn);
          if (t == Tn - 1){
            outp[Tn*Bsz*An + (size_t)b*Hn + n]           = hn;
            outp[Tn*Bsz*An + Bsz*Hn + (size_t)b*Hn + n]  = cn;
          }
        }
      }
    }
    if (t < Tn - 1) gbarH(gA, gG, gR, (int)gridDim.x, ++ph);
  }
}

extern "C" void kernel_launch(void* const* d_in, const int* in_sizes, int n_in,
                              void* d_out, int out_size, void* d_ws, size_t ws_size,
                              hipStream_t stream) {
  (void)in_sizes; (void)n_in; (void)out_size; (void)ws_size;
  const float* state    = (const float*)d_in[0];
  const float* demo     = (const float*)d_in[1];
  const int*   dlen     = (const int*)  d_in[2];
  const float* h0       = (const float*)d_in[5];
  const float* c0       = (const float*)d_in[6];
  const float* enc_Wih  = (const float*)d_in[7];
  const float* enc_Whh  = (const float*)d_in[8];
  const float* enc_bih  = (const float*)d_in[9];
  const float* enc_bhh  = (const float*)d_in[10];
  const float* attn_W   = (const float*)d_in[11];
  const float* attn_b   = (const float*)d_in[12];
  const float* comb_W   = (const float*)d_in[13];
  const float* comb_b   = (const float*)d_in[14];
  const float* lstm_Wih = (const float*)d_in[15];
  const float* lstm_Whh = (const float*)d_in[16];
  const float* lstm_bih = (const float*)d_in[17];
  const float* lstm_bhh = (const float*)d_in[18];
  const float* mid_W    = (const float*)d_in[19];
  const float* mid_b    = (const float*)d_in[20];
  const float* out_W    = (const float*)d_in[21];
  const float* out_b    = (const float*)d_in[22];
  float* ws   = (float*)d_ws;
  float* qout = (float*)d_out;

  // NON-ALIASED workspace layout (f32 words) — ~64.7 MiB total.
  // Invariant: every buffer that is bypass-written and cache-read has
  // exclusive addresses for the whole launch (write-once => cached reads safe).
  float* attnp  = ws + 0;          // 3,276,800   [B][L][H]
  float* CE     = ws + 3276800;    // 3,276,800 + 2048 pad (lenr over-read)
  float* preobs = ws + 6555648;    // 2,097,152   [T*B][H]
  float* demoT  = ws + 8652800;    //   819,200   [L][B][D]
  float* hencR  = ws + 9472000;    // 3,276,800   [L][B][H]
  float* xrow   = ws + 12748800;   // 2,097,152   [T][B][H]
  float* hhist  = ws + 14845952;   // 2,097,152   [T][B][H]
  int*   barB   = (int*)(ws + 16943104);  // 4,224 ints
  int* encA = barB;          int* encG = barB + 1024; int* encR = barB + 2048;
  int* decA = barB + 2112;   int* decG = barB + 3136; int* decR = barB + 4160;
  float* M2    = ws + 16947328;    // 9,216  [An][Hn]
  float* bias2 = ws + 16956544;    // 64

  hipMemsetAsync((void*)barB, 0, 4224*4, stream);

  demo_transpose_kernel<<<3200, 256, 0, stream>>>(demo, demoT);

  head_fold_kernel<<<An, 512, 0, stream>>>(mid_W, mid_b, out_W, out_b, M2, bias2);

  // preobs[(t,b)][n] = state[t,b,:] . comb_W[n, 512:640]
  gemm_nt_kernel<<<dim3(Tn*Bsz/64, Hn/64), 256, 0, stream>>>(
      state, Dn, comb_W + Hn, Hn + Dn, nullptr, preobs, Hn, Dn);

  enc_scan_kernel<<<256, 512, 0, stream>>>(
      demoT, enc_Wih, enc_Whh, enc_bih, enc_bhh, attn_W, attn_b, comb_W,
      hencR, attnp, CE, encA, encG, encR);

  dec_scan_kernel<<<256, 512, 0, stream>>>(
      h0, c0, attnp, CE, preobs, dlen, lstm_Wih, lstm_Whh, lstm_bih, lstm_bhh,
      comb_b, xrow, hhist, qout, decA, decG, decR);

  // q = hhist @ M2^T + bias2
  qhead_kernel<<<Tn, 256, 0, stream>>>(hhist, M2, bias2, qout);
}